// Round 3
// baseline (426.135 us; speedup 1.0000x reference)
//
#include <hip/hip_runtime.h>
#include <hip/hip_fp16.h>

#define BB 2
#define DX 160
#define DY 160
#define DZ 160

constexpr int    VOL        = DX * DY * DZ;          // 4,096,000
constexpr int    NVOX       = BB * VOL;              // 8,192,000
constexpr size_t PACK_BYTES = (size_t)NVOX * 32;     // 262,144,000 B

// ---------------------------------------------------------------------------
// Pack: cell (b,x,y,z) -> 8 corners x 2ch fp16, corner order c = ix*4+iy*2+iz,
// each corner a __half2 (ch0,ch1). Cell = 32 B. Each thread packs a z-pair of
// cells (z0=2k, z0+1) sharing the middle z-plane, writing 64 B contiguous.
// ---------------------------------------------------------------------------
__global__ __launch_bounds__(256) void pack_kernel(const float* __restrict__ im,
                                                   float4* __restrict__ pk)
{
    constexpr int NZP = DZ / 2;          // 80 z-pairs
    constexpr int NT  = NVOX / 2;        // 4,096,000 threads
    int t = blockIdx.x * blockDim.x + threadIdx.x;
    if (t >= NT) return;

    int zp = t % NZP;
    int r  = t / NZP;
    int y  = r % DY;  r /= DY;
    int x  = r % DX;
    int b  = r / DX;

    const int z0 = 2 * zp;
    const int x1 = min(x + 1, DX - 1);
    const int y1 = min(y + 1, DY - 1);
    const int z2 = min(z0 + 2, DZ - 1);

    const float2* __restrict__ imf = (const float2*)im;

    // rows indexed rr = ix + 2*iy
    const int row[4] = {
        ((b * DX + x ) * DY + y ) * DZ,
        ((b * DX + x1) * DY + y ) * DZ,
        ((b * DX + x ) * DY + y1) * DZ,
        ((b * DX + x1) * DY + y1) * DZ
    };

    float4 p01[4];   // (z0 ch0, z0 ch1, z0+1 ch0, z0+1 ch1)
    float2 p2[4];    // (z2 ch0, z2 ch1)
#pragma unroll
    for (int rr = 0; rr < 4; ++rr) {
        p01[rr] = *(const float4*)(imf + row[rr] + z0);   // 16B-aligned (row,z0 even)
        p2[rr]  = imf[row[rr] + z2];
    }

    __half2 hA[8], hB[8];
#pragma unroll
    for (int ix = 0; ix < 2; ++ix) {
#pragma unroll
        for (int iy = 0; iy < 2; ++iy) {
            const int rr = ix + 2 * iy;
            const int c  = ix * 4 + iy * 2;
            const __half2 v0 = __floats2half2_rn(p01[rr].x, p01[rr].y);
            const __half2 v1 = __floats2half2_rn(p01[rr].z, p01[rr].w);
            const __half2 v2 = __floats2half2_rn(p2[rr].x,  p2[rr].y);
            hA[c]     = v0;  hA[c + 1] = v1;   // cell z0: corners z0, z0+1
            hB[c]     = v1;  hB[c + 1] = v2;   // cell z0+1: corners z0+1, z2
        }
    }

    float4* dst = pk + (size_t)(row[0] + z0) * 2;   // 64 B contiguous per thread
    dst[0] = *(const float4*)&hA[0];
    dst[1] = *(const float4*)&hA[4];
    dst[2] = *(const float4*)&hB[0];
    dst[3] = *(const float4*)&hB[4];
}

// ---------------------------------------------------------------------------
// Gather: one 32 B cell read per voxel; 4 consecutive voxels per thread.
// defgrid for 4 voxels = 12 floats = 3 aligned float4 loads.
// ---------------------------------------------------------------------------
__device__ __forceinline__ float2 trilerp_cell(const float4 A, const float4 B,
                                               float xd, float yd, float zd)
{
    union { float4 f4[2]; __half2 h2[8]; } u;
    u.f4[0] = A;
    u.f4[1] = B;

    const float xm = 1.0f - xd, ym = 1.0f - yd, zm = 1.0f - zd;
    const float wx[2] = { xm, xd };
    const float wy[2] = { ym, yd };
    const float wz[2] = { zm, zd };

    float rx = 0.0f, ry = 0.0f;
#pragma unroll
    for (int c = 0; c < 8; ++c) {
        const float w = wx[(c >> 2) & 1] * wy[(c >> 1) & 1] * wz[c & 1];
        const float2 v = __half22float2(u.h2[c]);
        rx += w * v.x;
        ry += w * v.y;
    }
    return make_float2(rx, ry);
}

__global__ __launch_bounds__(256) void gather_kernel(const float4* __restrict__ pk,
                                                     const float4* __restrict__ defgrid4,
                                                     float2* __restrict__ out)
{
    constexpr int NT = NVOX / 4;         // 2,048,000 threads
    const int t = blockIdx.x * blockDim.x + threadIdx.x;
    if (t >= NT) return;

    const float4 g0 = defgrid4[(size_t)t * 3 + 0];
    const float4 g1 = defgrid4[(size_t)t * 3 + 1];
    const float4 g2 = defgrid4[(size_t)t * 3 + 2];

    const float cx[4] = { g0.x, g0.w, g1.z, g2.y };
    const float cy[4] = { g0.y, g1.x, g1.w, g2.z };
    const float cz[4] = { g0.z, g1.y, g2.x, g2.w };

    const int i0 = 4 * t;

    float  xd[4], yd[4], zd[4];
    size_t cidx[4];
#pragma unroll
    for (int j = 0; j < 4; ++j) {
        const int xi = min(max((int)floorf(cx[j]), 0), DX - 1);
        const int yi = min(max((int)floorf(cy[j]), 0), DY - 1);
        const int zi = min(max((int)floorf(cz[j]), 0), DZ - 1);
        xd[j] = cx[j] - (float)xi;
        yd[j] = cy[j] - (float)yi;
        zd[j] = cz[j] - (float)zi;
        const int b = (i0 + j) >= VOL ? 1 : 0;
        cidx[j] = (size_t)(((b * DX + xi) * DY + yi) * DZ + zi) * 2;
    }

    float4 A[4], Bv[4];
#pragma unroll
    for (int j = 0; j < 4; ++j) {        // issue all 8 loads before consuming
        A[j]  = pk[cidx[j]];
        Bv[j] = pk[cidx[j] + 1];
    }

    float2 r[4];
#pragma unroll
    for (int j = 0; j < 4; ++j)
        r[j] = trilerp_cell(A[j], Bv[j], xd[j], yd[j], zd[j]);

    float4* o4 = (float4*)(out + i0);    // 32 B contiguous per thread
    o4[0] = make_float4(r[0].x, r[0].y, r[1].x, r[1].y);
    o4[1] = make_float4(r[2].x, r[2].y, r[3].x, r[3].y);
}

// ---------------------------------------------------------------------------
// Fallback direct kernel in case ws_size < PACK_BYTES.
// ---------------------------------------------------------------------------
__global__ __launch_bounds__(256) void trilerp3d_direct(
    const float* __restrict__ im,
    const float* __restrict__ defgrid,
    float*       __restrict__ out)
{
    int idx = blockIdx.x * blockDim.x + threadIdx.x;
    if (idx >= NVOX) return;

    const float x = defgrid[idx * 3 + 0];
    const float y = defgrid[idx * 3 + 1];
    const float z = defgrid[idx * 3 + 2];

    const int x0u = (int)floorf(x);
    const int y0u = (int)floorf(y);
    const int z0u = (int)floorf(z);

    const int x0 = min(max(x0u, 0), DX - 1);
    const int x1 = min(max(x0u + 1, 0), DX - 1);
    const int y0 = min(max(y0u, 0), DY - 1);
    const int y1 = min(max(y0u + 1, 0), DY - 1);
    const int z0 = min(max(z0u, 0), DZ - 1);
    const int z1 = min(max(z0u + 1, 0), DZ - 1);

    const float xd = x - (float)x0;
    const float yd = y - (float)y0;
    const float zd = z - (float)z0;

    const int b    = idx / VOL;
    const int base = b * VOL;

    const float2* __restrict__ imf = (const float2*)im;

    const int px0 = base + x0 * (DY * DZ);
    const int px1 = base + x1 * (DY * DZ);
    const int oy0 = y0 * DZ;
    const int oy1 = y1 * DZ;

    const float2 Ia = imf[px0 + oy0 + z0];
    const float2 Ib = imf[px0 + oy0 + z1];
    const float2 Ic = imf[px0 + oy1 + z0];
    const float2 Id = imf[px0 + oy1 + z1];
    const float2 Ie = imf[px1 + oy0 + z0];
    const float2 If = imf[px1 + oy0 + z1];
    const float2 Ig = imf[px1 + oy1 + z0];
    const float2 Ih = imf[px1 + oy1 + z1];

    const float xm = 1.0f - xd, ym = 1.0f - yd, zm = 1.0f - zd;

    float cae_x = Ia.x * xm + Ie.x * xd;
    float cae_y = Ia.y * xm + Ie.y * xd;
    float cbf_x = Ib.x * xm + If.x * xd;
    float cbf_y = Ib.y * xm + If.y * xd;
    float ccg_x = Ic.x * xm + Ig.x * xd;
    float ccg_y = Ic.y * xm + Ig.y * xd;
    float cdh_x = Id.x * xm + Ih.x * xd;
    float cdh_y = Id.y * xm + Ih.y * xd;

    float c0_x = cae_x * ym + ccg_x * yd;
    float c0_y = cae_y * ym + ccg_y * yd;
    float c1_x = cbf_x * ym + cdh_x * yd;
    float c1_y = cbf_y * ym + cdh_y * yd;

    float2 r;
    r.x = c0_x * zm + c1_x * zd;
    r.y = c0_y * zm + c1_y * zd;
    ((float2*)out)[idx] = r;
}

extern "C" void kernel_launch(void* const* d_in, const int* in_sizes, int n_in,
                              void* d_out, int out_size, void* d_ws, size_t ws_size,
                              hipStream_t stream) {
    const float* im      = (const float*)d_in[0];
    const float* defgrid = (const float*)d_in[1];
    float*       out     = (float*)d_out;

    const int block = 256;

    if (ws_size >= PACK_BYTES) {
        float4* pk = (float4*)d_ws;
        const int gridP = (NVOX / 2 + block - 1) / block;
        pack_kernel<<<gridP, block, 0, stream>>>(im, pk);
        const int gridG = (NVOX / 4 + block - 1) / block;
        gather_kernel<<<gridG, block, 0, stream>>>(pk, (const float4*)defgrid, (float2*)out);
    } else {
        const int grid = (NVOX + block - 1) / block;
        trilerp3d_direct<<<grid, block, 0, stream>>>(im, defgrid, out);
    }
}